// Round 10
// baseline (153.057 us; speedup 1.0000x reference)
//
#include <hip/hip_runtime.h>

// VQ-VAE forward, two-stage argmin, conversion fused into the GEMM:
//   1) conv_w: weight -> f16 W image + wsq + usage=0 + done=0 (tiny)
//   2) vq_coarse: fp16 MFMA GEMM reading f32 inputs directly (reg-staged cvt,
//      XOR-swizzled A LDS), fused top-2-per-nb argmin + xsq (nb==0 blocks)
//   3) vq_pickgather: resolve argmin (exact f32 refine for contended ~8%),
//      usage + loss (identity) + register-transpose gather + fused final reduce
// d_out: [0,8388608) quantized f32 | [8388608] loss | [8388609,+1024) usage
// d_ws: Wimg 512K | wsq 4K | best2 2M | partial 2K | done 1K | xsq 128K

typedef _Float16 f16;
typedef __attribute__((ext_vector_type(8))) f16 f16x8;
typedef __attribute__((ext_vector_type(4))) float f32x4;
typedef unsigned int u32;
typedef unsigned long long u64;

#define NQ 8388608

__device__ __forceinline__ u32 sortkey(float f) {
    u32 u = __float_as_uint(f);
    return (u & 0x80000000u) ? ~u : (u | 0x80000000u);
}
__device__ __forceinline__ float inv_sortkey(u32 u) {
    return (u & 0x80000000u) ? __uint_as_float(u & 0x7FFFFFFFu) : __uint_as_float(~u);
}

// ---- weight -> W-f16 image [nb 0..7][t 0..7][cg 0..3][col 0..127][16B] ----
extern "C" __global__ __launch_bounds__(256) void conv_w(const float* __restrict__ w,
                                                         char* __restrict__ Wimg,
                                                         float* __restrict__ wsq,
                                                         float* __restrict__ usage,
                                                         u32* __restrict__ done) {
    int blk = blockIdx.x, tid = threadIdx.x;
    if (blk == 0 && tid == 0) done[0] = 0;
    int gid = blk * 256 + tid;  // 32768 = 1024 n x 32 dc
    int n = gid >> 5, dc = gid & 31;
    const float* src = w + n * 256 + dc * 8;
    float4 v0 = *(const float4*)src;
    float4 v1 = *(const float4*)(src + 4);
    float xs[8] = {v0.x, v0.y, v0.z, v0.w, v1.x, v1.y, v1.z, v1.w};
    union { f16 h[8]; uint4 v; } pk;
    float sq = 0.0f;
    #pragma unroll
    for (int j = 0; j < 8; ++j) {
        pk.h[j] = (f16)xs[j];
        sq += xs[j] * xs[j];
    }
    int nb = n >> 7, col = n & 127;
    *(uint4*)(Wimg + (size_t)nb * 65536 + (dc >> 2) * 8192 + (dc & 3) * 2048 + col * 16) = pk.v;
    #pragma unroll
    for (int m = 1; m <= 16; m <<= 1) sq += __shfl_xor(sq, m, 64);
    if ((tid & 31) == 0) { wsq[n] = sq; usage[n] = 0.0f; }
}

// ---- coarse fp16 GEMM 128x128xK256, A staged from f32 with in-reg cvt ----
extern "C" __global__ __launch_bounds__(256) void vq_coarse(const float* __restrict__ inp,
                                                            const char* __restrict__ Wimg,
                                                            const float* __restrict__ wsq,
                                                            u32* __restrict__ best2,
                                                            float* __restrict__ xsq) {
    __shared__ __align__(16) char smem[32768];  // [buf][A 8K | B 8K] x2
    __shared__ u32 red2[128][2][2];
    const int tid = threadIdx.x, lane = tid & 63, wv = tid >> 6;
    const int wm = wv >> 1, wn = wv & 1;
    const int rm = wm * 64, cn = wn * 64;
    const int cg = lane >> 4, rl = lane & 15;
    int bid = blockIdx.x;
    int lb = (bid & 7) * 256 + (bid >> 3);  // XCD-chunked swizzle (2048 % 8 == 0)
    const int mb = lb >> 3, nb = lb & 7;

    const int scg = wv;      // staging d-octet group
    const int pidx = lane;   // points 2*pidx, 2*pidx+1
    const float* Abase = inp + (size_t)(mb >> 3) * 262144 + (mb & 7) * 128 + 2 * pidx;
    const char* Bg = Wimg + (size_t)nb * 65536;

    f32x4 acc[4][4];
    #pragma unroll
    for (int i = 0; i < 4; ++i)
        #pragma unroll
        for (int j = 0; j < 4; ++j) acc[i][j] = (f32x4){0.f, 0.f, 0.f, 0.f};

    float2 ar[8];
    float sq0 = 0.0f, sq1 = 0.0f;

#define LOADA(T_)                                                                        \
    do {                                                                                 \
        _Pragma("unroll") for (int j = 0; j < 8; ++j)                                    \
            ar[j] = *(const float2*)(Abase + (size_t)((T_)*32 + scg * 8 + j) * 1024);    \
    } while (0)

#define STAGEB(T_)                                                                      \
    do {                                                                                \
        const char* gb = Bg + (size_t)(T_)*8192;                                        \
        char* lb2 = smem + ((T_)&1) * 16384 + 8192;                                     \
        __builtin_amdgcn_global_load_lds(                                               \
            (const __attribute__((address_space(1))) u32*)(gb + tid * 16),              \
            (__attribute__((address_space(3))) u32*)(lb2 + tid * 16), 16, 0, 0);        \
        __builtin_amdgcn_global_load_lds(                                               \
            (const __attribute__((address_space(1))) u32*)(gb + tid * 16 + 4096),       \
            (__attribute__((address_space(3))) u32*)(lb2 + tid * 16 + 4096), 16, 0, 0); \
    } while (0)

#define WRITEA(T_)                                                                      \
    do {                                                                                \
        union { f16 h[8]; uint4 v; } p0, p1;                                            \
        _Pragma("unroll") for (int j = 0; j < 8; ++j) {                                 \
            p0.h[j] = (f16)ar[j].x;                                                     \
            p1.h[j] = (f16)ar[j].y;                                                     \
            sq0 = fmaf(ar[j].x, ar[j].x, sq0);                                          \
            sq1 = fmaf(ar[j].y, ar[j].y, sq1);                                          \
        }                                                                               \
        char* la = smem + ((T_)&1) * 16384;                                             \
        int pt0 = 2 * pidx, pt1 = pt0 + 1;                                              \
        *(uint4*)(la + ((scg * 2048 + pt0 * 16) ^ (((pt0 >> 3) & 7) << 4))) = p0.v;     \
        *(uint4*)(la + ((scg * 2048 + pt1 * 16) ^ (((pt1 >> 3) & 7) << 4))) = p1.v;     \
    } while (0)

    // prologue
    LOADA(0);
    __builtin_amdgcn_sched_barrier(0);
    STAGEB(0);
    asm volatile("s_waitcnt vmcnt(2)" ::: "memory");  // A regs ready (B lds may fly)
    WRITEA(0);
    asm volatile("s_waitcnt vmcnt(0) lgkmcnt(0)" ::: "memory");
    __builtin_amdgcn_s_barrier();

    for (int T = 0; T < 8; ++T) {
        if (T < 7) {
            LOADA(T + 1);
            __builtin_amdgcn_sched_barrier(0);
            STAGEB(T + 1);
        }
        const char* Ab = smem + (T & 1) * 16384;
        const char* Bb = Ab + 8192 + cg * 2048;
        f16x8 af[4], bf[4];
        #pragma unroll
        for (int f = 0; f < 4; ++f) {
            int pt = rm + f * 16 + rl;
            af[f] = *(const f16x8*)(Ab + ((cg * 2048 + pt * 16) ^ (((pt >> 3) & 7) << 4)));
            bf[f] = *(const f16x8*)(Bb + (cn + f * 16 + rl) * 16);
        }
        __builtin_amdgcn_sched_barrier(0);
        asm volatile("s_waitcnt lgkmcnt(0)" ::: "memory");
        __builtin_amdgcn_sched_barrier(0);
        __builtin_amdgcn_s_setprio(1);
        #pragma unroll
        for (int fi = 0; fi < 4; ++fi)
            #pragma unroll
            for (int fj = 0; fj < 4; ++fj)
                acc[fi][fj] = __builtin_amdgcn_mfma_f32_16x16x32_f16(af[fi], bf[fj],
                                                                    acc[fi][fj], 0, 0, 0);
        __builtin_amdgcn_s_setprio(0);
        __builtin_amdgcn_sched_barrier(0);
        if (T < 7) {
            asm volatile("s_waitcnt vmcnt(2)" ::: "memory");  // A(T+1) regs landed
            WRITEA(T + 1);
        }
        asm volatile("s_waitcnt vmcnt(0) lgkmcnt(0)" ::: "memory");
        __builtin_amdgcn_s_barrier();
    }
#undef LOADA
#undef STAGEB
#undef WRITEA

    // xsq (fixed-order 4-way combine) — only nb==0 blocks write
    if (nb == 0) {
        float* sqs = (float*)smem;  // staging area free after K-loop
        sqs[(2 * pidx) * 4 + scg] = sq0;
        sqs[(2 * pidx + 1) * 4 + scg] = sq1;
        __syncthreads();
        if (tid < 128)
            xsq[mb * 128 + tid] =
                (sqs[tid * 4] + sqs[tid * 4 + 1]) + (sqs[tid * 4 + 2] + sqs[tid * 4 + 3]);
        __syncthreads();
    }

    // top-2 per point within this nb: key = (sortkey(dist) & ~1023) | n
    float wq[4];
    #pragma unroll
    for (int fj = 0; fj < 4; ++fj) wq[fj] = wsq[nb * 128 + cn + fj * 16 + rl];

    #pragma unroll
    for (int fi = 0; fi < 4; ++fi) {
        #pragma unroll
        for (int r = 0; r < 4; ++r) {
            u32 b = 0xFFFFFFFFu, s = 0xFFFFFFFFu;
            #pragma unroll
            for (int fj = 0; fj < 4; ++fj) {
                float dist = wq[fj] - 2.0f * acc[fi][fj][r];
                u32 n = (u32)(nb * 128 + cn + fj * 16 + rl);
                u32 cand = (sortkey(dist) & 0xFFFFFC00u) | n;
                if (cand < b) { s = b; b = cand; }
                else if (cand < s) { s = cand; }
            }
            #pragma unroll
            for (int m2 = 1; m2 <= 8; m2 <<= 1) {
                u32 qb = (u32)__shfl_xor((int)b, m2, 64);
                u32 qs = (u32)__shfl_xor((int)s, m2, 64);
                u32 hi = b > qb ? b : qb;
                b = b < qb ? b : qb;
                s = s < qs ? s : qs;
                s = s < hi ? s : hi;
            }
            if (rl == 0) {
                int mloc = rm + fi * 16 + cg * 4 + r;
                red2[mloc][wn][0] = b;
                red2[mloc][wn][1] = s;
            }
        }
    }
    __syncthreads();
    if (tid < 128) {
        u32 b0 = red2[tid][0][0], s0 = red2[tid][0][1];
        u32 b1 = red2[tid][1][0], s1 = red2[tid][1][1];
        u32 B = b0 < b1 ? b0 : b1;
        u32 hi = b0 > b1 ? b0 : b1;
        u32 S = s0 < s1 ? s0 : s1;
        S = S < hi ? S : hi;
        u32* dst = best2 + ((size_t)mb * 128 + tid) * 16 + nb * 2;
        dst[0] = B;
        dst[1] = S;
    }
}

// ---- pick + gather fused: resolve, usage, loss, register-transpose gather ----
extern "C" __global__ __launch_bounds__(256) void vq_pickgather(const float* __restrict__ inp,
                                                                const float* __restrict__ w,
                                                                const u32* __restrict__ best2,
                                                                const float* __restrict__ xsq,
                                                                float* __restrict__ outq,
                                                                float* __restrict__ usage,
                                                                float* __restrict__ partial,
                                                                u32* __restrict__ done,
                                                                float* __restrict__ loss) {
    __shared__ int sidx[64];
    __shared__ float sld[64];
    __shared__ u32 s_cp[32];
    __shared__ u32 s_cm[32];
    __shared__ u32 s_ck[32][8];
    __shared__ u64 s_res[32];
    __shared__ int s_C;
    __shared__ u32 amlast;

    int blk = blockIdx.x, t = threadIdx.x;
    int lane = t & 63, wv = t >> 6;
    int p0 = blk * 64;
    int b = p0 >> 10, hw0 = p0 & 1023;
    if (t == 0) s_C = 0;
    __syncthreads();

    if (t < 64) {
        int p = p0 + t;
        const uint4* cp = (const uint4*)(best2 + (size_t)p * 16);
        uint4 q0 = cp[0], q1 = cp[1], q2 = cp[2], q3 = cp[3];
        u32 ca[16] = {q0.x, q0.y, q0.z, q0.w, q1.x, q1.y, q1.z, q1.w,
                      q2.x, q2.y, q2.z, q2.w, q3.x, q3.y, q3.z, q3.w};
        u32 minc = ca[0];
        #pragma unroll
        for (int c = 1; c < 16; ++c) minc = ca[c] < minc ? ca[c] : minc;
        float dmin = inv_sortkey(minc & 0xFFFFFC00u);
        float thr = dmin + 1.0f;  // coarse err (~0.05) << 1.0 << typical gap (~13)
        u32 ks[8];
        int m = 0;
        #pragma unroll
        for (int c = 0; c < 16; ++c) {
            if (inv_sortkey(ca[c] & 0xFFFFFC00u) <= thr) {
                if (m < 8) ks[m] = ca[c] & 1023u;
                ++m;
            }
        }
        if (m > 8) m = 8;
        float xs = xsq[p];
        if (m <= 1) {  // uncontended: coarse key IS the argmin; loss via identity
            sidx[t] = (int)(minc & 1023u);
            sld[t] = xs + dmin;
        } else {
            int slot = atomicAdd(&s_C, 1);
            if (slot < 32) {
                s_cp[slot] = (u32)t;
                s_cm[slot] = (u32)m;
                for (int i = 0; i < m; ++i) s_ck[slot][i] = ks[i];
            } else {  // statistically impossible overflow: graceful fallback
                sidx[t] = (int)(minc & 1023u);
                sld[t] = xs + dmin;
            }
        }
    }
    __syncthreads();
    int C = s_C < 32 ? s_C : 32;
    // exact refine: one wave per contended point; x column read once
    for (int s = wv; s < C; s += 4) {
        int pp = p0 + (int)s_cp[s];
        const float* xc = inp + (size_t)(pp >> 10) * 262144 + (pp & 1023);
        float x0 = xc[(size_t)(lane * 4 + 0) * 1024];
        float x1 = xc[(size_t)(lane * 4 + 1) * 1024];
        float x2 = xc[(size_t)(lane * 4 + 2) * 1024];
        float x3 = xc[(size_t)(lane * 4 + 3) * 1024];
        u64 best = ~0ull;
        int m = (int)s_cm[s];
        for (int c = 0; c < m; ++c) {
            int k = (int)s_ck[s][c];
            float4 wv4 = *(const float4*)(w + (size_t)k * 256 + lane * 4);
            float d0 = x0 - wv4.x, d1 = x1 - wv4.y, d2 = x2 - wv4.z, d3 = x3 - wv4.w;
            float a2 = fmaf(d0, d0, fmaf(d1, d1, fmaf(d2, d2, d3 * d3)));
            #pragma unroll
            for (int m2 = 1; m2 <= 32; m2 <<= 1) a2 += __shfl_xor(a2, m2, 64);
            u64 key = ((u64)sortkey(a2) << 32) | (u32)k;  // tie -> lowest k
            best = key < best ? key : best;
        }
        if (lane == 0) s_res[s] = best;
    }
    __syncthreads();
    if (t < C) {
        u64 r = s_res[t];
        sidx[s_cp[t]] = (int)(r & 1023u);
        sld[s_cp[t]] = inv_sortkey((u32)(r >> 32));  // exact ||x-w||^2
    }
    __syncthreads();
    if (t < 64) atomicAdd(usage + sidx[t], 1.0f);  // integer-valued f32: exact

    // register-transpose gather: thread = (dseg 0..15) x (ptq 0..15)
    {
        int ptq = t & 15, dseg = t >> 4;
        int k0 = sidx[ptq * 4 + 0], k1 = sidx[ptq * 4 + 1];
        int k2 = sidx[ptq * 4 + 2], k3 = sidx[ptq * 4 + 3];
        const float* w0 = w + (size_t)k0 * 256 + dseg * 16;
        const float* w1 = w + (size_t)k1 * 256 + dseg * 16;
        const float* w2 = w + (size_t)k2 * 256 + dseg * 16;
        const float* w3 = w + (size_t)k3 * 256 + dseg * 16;
        float* ob = outq + (size_t)b * 262144 + hw0 + ptq * 4;
        #pragma unroll
        for (int q = 0; q < 4; ++q) {
            float4 a = *(const float4*)(w0 + q * 4);
            float4 bb = *(const float4*)(w1 + q * 4);
            float4 c = *(const float4*)(w2 + q * 4);
            float4 dd = *(const float4*)(w3 + q * 4);
            int d = dseg * 16 + q * 4;
            *(float4*)(ob + (size_t)(d + 0) * 1024) = (float4){a.x, bb.x, c.x, dd.x};
            *(float4*)(ob + (size_t)(d + 1) * 1024) = (float4){a.y, bb.y, c.y, dd.y};
            *(float4*)(ob + (size_t)(d + 2) * 1024) = (float4){a.z, bb.z, c.z, dd.z};
            *(float4*)(ob + (size_t)(d + 3) * 1024) = (float4){a.w, bb.w, c.w, dd.w};
        }
    }

    // block loss partial (fixed-order) + fused final reduce via done counter
    float lsum = (t < 64) ? sld[t] : 0.0f;
    if (wv == 0) {
        #pragma unroll
        for (int off = 32; off >= 1; off >>= 1) lsum += __shfl_xor(lsum, off, 64);
    }
    if (t == 0) {
        partial[blk] = lsum;
        __threadfence();
        amlast = (atomicAdd(done, 1u) == 511u) ? 1u : 0u;
    }
    __syncthreads();
    if (amlast) {
        __threadfence();  // acquire: other blocks' partial writes
        __shared__ float sm[256];
        sm[t] = partial[t] + partial[t + 256];
        __syncthreads();
        #pragma unroll
        for (int off = 128; off >= 1; off >>= 1) {
            if (t < off) sm[t] += sm[t + off];
            __syncthreads();
        }
        if (t == 0) loss[0] = sm[0] * (1.25f / 8388608.0f);
    }
}

extern "C" void kernel_launch(void* const* d_in, const int* in_sizes, int n_in,
                              void* d_out, int out_size, void* d_ws, size_t ws_size,
                              hipStream_t stream) {
    const float* inp = (const float*)d_in[0];
    const float* w = (const float*)d_in[1];
    float* outq = (float*)d_out;
    float* loss = outq + NQ;
    float* usage = outq + NQ + 1;

    char* ws = (char*)d_ws;
    char* Wimg = ws;                          // 512 KiB
    float* wsq = (float*)(ws + 524288);       // 4 KiB
    u32* best2 = (u32*)(ws + 528384);         // 2 MiB
    float* partial = (float*)(ws + 2625536);  // 2 KiB
    u32* done = (u32*)(ws + 2627584);         // 1 KiB
    float* xsq = (float*)(ws + 2628608);      // 128 KiB

    conv_w<<<128, 256, 0, stream>>>(w, Wimg, wsq, usage, done);
    vq_coarse<<<2048, 256, 0, stream>>>(inp, Wimg, wsq, best2, xsq);
    vq_pickgather<<<512, 256, 0, stream>>>(inp, w, best2, xsq, outq, usage, partial, done,
                                           loss);
}

// Round 11
// 93.525 us; speedup vs baseline: 1.6365x; 1.6365x over previous
//
#include <hip/hip_runtime.h>

// VQ-VAE forward, two-stage argmin:
//   1) vq_conv: inputs -> f16 A image + xsq partials; weight -> f16 W image + wsq
//   2) vq_coarse: fp16 MFMA GEMM (K=256) + fused top-2-per-nb candidate extraction
//   3) vq_pickgather: resolve argmin (exact f32 refine only for contended ~8%),
//      usage + loss (identity) + register-transpose gather + fused final reduce
// d_out: [0,8388608) quantized f32 | [8388608] loss | [8388609,+1024) usage
// d_out[0,16MiB) doubles as the f16 A-image (conv -> coarse), overwritten by gather.
// d_ws: Wimg 512K | wsq 4K | best2 2M | partial 2K | done 1K | xsqp 512K

typedef _Float16 f16;
typedef __attribute__((ext_vector_type(8))) f16 f16x8;
typedef __attribute__((ext_vector_type(4))) float f32x4;
typedef unsigned int u32;
typedef unsigned long long u64;

#define NQ 8388608

__device__ __forceinline__ u32 sortkey(float f) {
    u32 u = __float_as_uint(f);
    return (u & 0x80000000u) ? ~u : (u | 0x80000000u);
}
__device__ __forceinline__ float inv_sortkey(u32 u) {
    return (u & 0x80000000u) ? __uint_as_float(u & 0x7FFFFFFFu) : __uint_as_float(~u);
}

// ---- merged conversion kernel ----
// blocks 0..1023: inputs -> A-f16 image (block = mb*4+dcb) + xsq partials
// blocks 1024..1151: weight -> W-f16 image + wsq + usage=0 + done=0
extern "C" __global__ __launch_bounds__(256) void vq_conv(const float* __restrict__ inp,
                                                          const float* __restrict__ w,
                                                          char* __restrict__ Aimg,
                                                          char* __restrict__ Wimg,
                                                          float* __restrict__ wsq,
                                                          float* __restrict__ usage,
                                                          u32* __restrict__ done,
                                                          float* __restrict__ xsqp) {
    int blk = blockIdx.x, tid = threadIdx.x;
    if (blk < 1024) {
        __shared__ float xt[64 * 128];
        int mb = blk >> 2, dcb = blk & 3;
        int b = mb >> 3, hw0 = (mb & 7) * 128;
        const float* base = inp + (size_t)b * 262144 + hw0;
        char* Ab = Aimg + (size_t)mb * 65536;
        #pragma unroll
        for (int it = 0; it < 8; ++it) {
            int e = it * 256 + tid;
            int dd = e >> 5, h4 = e & 31;
            float4 v = *(const float4*)(base + (size_t)(dcb * 64 + dd) * 1024 + h4 * 4);
            *(float4*)(xt + dd * 128 + h4 * 4) = v;
        }
        __syncthreads();
        #pragma unroll
        for (int it2 = 0; it2 < 4; ++it2) {
            int task = it2 * 256 + tid;
            int g = task >> 7, row = task & 127;
            union { f16 h[8]; uint4 v; } pk;
            #pragma unroll
            for (int j = 0; j < 8; ++j) pk.h[j] = (f16)xt[(g * 8 + j) * 128 + row];
            int t_img = dcb * 2 + (g >> 2), cg = g & 3;
            *(uint4*)(Ab + (size_t)t_img * 8192 + cg * 2048 + row * 16) = pk.v;
        }
        if (tid < 128) {
            float s = 0.0f;
            #pragma unroll 8
            for (int dd = 0; dd < 64; ++dd) {
                float x = xt[dd * 128 + tid];
                s = fmaf(x, x, s);
            }
            xsqp[dcb * 32768 + mb * 128 + tid] = s;
        }
    } else {
        if (blk == 1024 && tid == 0) done[0] = 0;
        int gid = (blk - 1024) * 256 + tid;  // 32768 = 1024 n x 32 dc
        int n = gid >> 5, dc = gid & 31;
        const float* src = w + n * 256 + dc * 8;
        float4 v0 = *(const float4*)src;
        float4 v1 = *(const float4*)(src + 4);
        float xs[8] = {v0.x, v0.y, v0.z, v0.w, v1.x, v1.y, v1.z, v1.w};
        union { f16 h[8]; uint4 v; } pk;
        float sq = 0.0f;
        #pragma unroll
        for (int j = 0; j < 8; ++j) {
            pk.h[j] = (f16)xs[j];
            sq += xs[j] * xs[j];
        }
        int nb = n >> 7, col = n & 127;
        *(uint4*)(Wimg + (size_t)nb * 65536 + (dc >> 2) * 8192 + (dc & 3) * 2048 + col * 16) = pk.v;
        #pragma unroll
        for (int m = 1; m <= 16; m <<= 1) sq += __shfl_xor(sq, m, 64);
        if ((tid & 31) == 0) { wsq[n] = sq; usage[n] = 0.0f; }
    }
}

// ---- coarse fp16 GEMM 128x128xK256 + fused top-2-per-nb argmin ----
extern "C" __global__ __launch_bounds__(256) void vq_coarse(const char* __restrict__ Aimg,
                                                            const char* __restrict__ Wimg,
                                                            const float* __restrict__ wsq,
                                                            u32* __restrict__ best2) {
    __shared__ __align__(16) char smem[32768];  // 2 bufs x (A 8K + B 8K)
    __shared__ u32 red2[128][2][2];
    const int tid = threadIdx.x, lane = tid & 63, wv = tid >> 6;
    const int wm = wv >> 1, wn = wv & 1;
    const int rm = wm * 64, cn = wn * 64;
    const int cg = lane >> 4, rl = lane & 15;
    int bid = blockIdx.x;
    int lb = (bid & 7) * 256 + (bid >> 3);  // XCD-chunked swizzle (2048 % 8 == 0)
    const int mb = lb >> 3, nb = lb & 7;

    const char* Ag = Aimg + (size_t)mb * 65536;
    const char* Bg = Wimg + (size_t)nb * 65536;

    f32x4 acc[4][4];
    #pragma unroll
    for (int i = 0; i < 4; ++i)
        #pragma unroll
        for (int j = 0; j < 4; ++j) acc[i][j] = (f32x4){0.f, 0.f, 0.f, 0.f};

    auto stage = [&](int T) {
        const char* ga = Ag + (size_t)T * 8192;
        const char* gb = Bg + (size_t)T * 8192;
        char* la = smem + (T & 1) * 16384;
        char* lb2 = la + 8192;
        __builtin_amdgcn_global_load_lds(
            (const __attribute__((address_space(1))) u32*)(ga + tid * 16),
            (__attribute__((address_space(3))) u32*)(la + tid * 16), 16, 0, 0);
        __builtin_amdgcn_global_load_lds(
            (const __attribute__((address_space(1))) u32*)(ga + tid * 16 + 4096),
            (__attribute__((address_space(3))) u32*)(la + tid * 16 + 4096), 16, 0, 0);
        __builtin_amdgcn_global_load_lds(
            (const __attribute__((address_space(1))) u32*)(gb + tid * 16),
            (__attribute__((address_space(3))) u32*)(lb2 + tid * 16), 16, 0, 0);
        __builtin_amdgcn_global_load_lds(
            (const __attribute__((address_space(1))) u32*)(gb + tid * 16 + 4096),
            (__attribute__((address_space(3))) u32*)(lb2 + tid * 16 + 4096), 16, 0, 0);
    };

    stage(0);
    asm volatile("s_waitcnt vmcnt(0)" ::: "memory");
    __builtin_amdgcn_s_barrier();

    for (int T = 0; T < 8; ++T) {
        if (T < 7) stage(T + 1);
        const char* Ab = smem + (T & 1) * 16384 + cg * 2048;
        const char* Bb = Ab + 8192;
        f16x8 af[4], bf[4];
        #pragma unroll
        for (int f = 0; f < 4; ++f) {
            af[f] = *(const f16x8*)(Ab + (rm + f * 16 + rl) * 16);
            bf[f] = *(const f16x8*)(Bb + (cn + f * 16 + rl) * 16);
        }
        __builtin_amdgcn_sched_barrier(0);
        asm volatile("s_waitcnt lgkmcnt(0)" ::: "memory");
        __builtin_amdgcn_sched_barrier(0);
        __builtin_amdgcn_s_setprio(1);
        #pragma unroll
        for (int fi = 0; fi < 4; ++fi)
            #pragma unroll
            for (int fj = 0; fj < 4; ++fj)
                acc[fi][fj] = __builtin_amdgcn_mfma_f32_16x16x32_f16(af[fi], bf[fj],
                                                                    acc[fi][fj], 0, 0, 0);
        __builtin_amdgcn_s_setprio(0);
        __builtin_amdgcn_sched_barrier(0);
        asm volatile("s_waitcnt vmcnt(0)" ::: "memory");
        __builtin_amdgcn_s_barrier();
    }

    // top-2 per point within this nb: key = (sortkey(dist) & ~1023) | n
    float wq[4];
    #pragma unroll
    for (int fj = 0; fj < 4; ++fj) wq[fj] = wsq[nb * 128 + cn + fj * 16 + rl];

    #pragma unroll
    for (int fi = 0; fi < 4; ++fi) {
        #pragma unroll
        for (int r = 0; r < 4; ++r) {
            u32 b = 0xFFFFFFFFu, s = 0xFFFFFFFFu;
            #pragma unroll
            for (int fj = 0; fj < 4; ++fj) {
                float dist = wq[fj] - 2.0f * acc[fi][fj][r];
                u32 n = (u32)(nb * 128 + cn + fj * 16 + rl);
                u32 cand = (sortkey(dist) & 0xFFFFFC00u) | n;
                if (cand < b) { s = b; b = cand; }
                else if (cand < s) { s = cand; }
            }
            #pragma unroll
            for (int m2 = 1; m2 <= 8; m2 <<= 1) {
                u32 qb = (u32)__shfl_xor((int)b, m2, 64);
                u32 qs = (u32)__shfl_xor((int)s, m2, 64);
                u32 hi = b > qb ? b : qb;
                b = b < qb ? b : qb;
                s = s < qs ? s : qs;
                s = s < hi ? s : hi;
            }
            if (rl == 0) {
                int mloc = rm + fi * 16 + cg * 4 + r;
                red2[mloc][wn][0] = b;
                red2[mloc][wn][1] = s;
            }
        }
    }
    __syncthreads();
    if (tid < 128) {
        u32 b0 = red2[tid][0][0], s0 = red2[tid][0][1];
        u32 b1 = red2[tid][1][0], s1 = red2[tid][1][1];
        u32 B = b0 < b1 ? b0 : b1;
        u32 hi = b0 > b1 ? b0 : b1;
        u32 S = s0 < s1 ? s0 : s1;
        S = S < hi ? S : hi;
        u32* dst = best2 + ((size_t)mb * 128 + tid) * 16 + nb * 2;
        dst[0] = B;
        dst[1] = S;
    }
}

// ---- pick + gather fused: resolve, usage, loss, register-transpose gather ----
extern "C" __global__ __launch_bounds__(256) void vq_pickgather(const float* __restrict__ inp,
                                                                const float* __restrict__ w,
                                                                const u32* __restrict__ best2,
                                                                const float* __restrict__ xsqp,
                                                                float* __restrict__ outq,
                                                                float* __restrict__ usage,
                                                                float* __restrict__ partial,
                                                                u32* __restrict__ done,
                                                                float* __restrict__ loss) {
    __shared__ int sidx[64];
    __shared__ float sld[64];
    __shared__ u32 s_cp[32];
    __shared__ u32 s_cm[32];
    __shared__ u32 s_ck[32][8];
    __shared__ u64 s_res[32];
    __shared__ int s_C;
    __shared__ u32 amlast;

    int blk = blockIdx.x, t = threadIdx.x;
    int lane = t & 63, wv = t >> 6;
    int p0 = blk * 64;
    int b = p0 >> 10, hw0 = p0 & 1023;
    if (t == 0) s_C = 0;
    __syncthreads();

    if (t < 64) {
        int p = p0 + t;
        const uint4* cp = (const uint4*)(best2 + (size_t)p * 16);
        uint4 q0 = cp[0], q1 = cp[1], q2 = cp[2], q3 = cp[3];
        u32 ca[16] = {q0.x, q0.y, q0.z, q0.w, q1.x, q1.y, q1.z, q1.w,
                      q2.x, q2.y, q2.z, q2.w, q3.x, q3.y, q3.z, q3.w};
        u32 minc = ca[0];
        #pragma unroll
        for (int c = 1; c < 16; ++c) minc = ca[c] < minc ? ca[c] : minc;
        float dmin = inv_sortkey(minc & 0xFFFFFC00u);
        float thr = dmin + 1.0f;  // coarse err (~0.05) << 1.0 << typical gap (~13)
        u32 ks[8];
        int m = 0;
        #pragma unroll
        for (int c = 0; c < 16; ++c) {
            if (inv_sortkey(ca[c] & 0xFFFFFC00u) <= thr) {
                if (m < 8) ks[m] = ca[c] & 1023u;
                ++m;
            }
        }
        if (m > 8) m = 8;
        float xs = (xsqp[p] + xsqp[32768 + p]) + (xsqp[65536 + p] + xsqp[98304 + p]);
        if (m <= 1) {  // uncontended: coarse key IS the argmin; loss via identity
            sidx[t] = (int)(minc & 1023u);
            sld[t] = xs + dmin;
        } else {
            int slot = atomicAdd(&s_C, 1);
            if (slot < 32) {
                s_cp[slot] = (u32)t;
                s_cm[slot] = (u32)m;
                for (int i = 0; i < m; ++i) s_ck[slot][i] = ks[i];
            } else {  // statistically impossible overflow: graceful fallback
                sidx[t] = (int)(minc & 1023u);
                sld[t] = xs + dmin;
            }
        }
    }
    __syncthreads();
    int C = s_C < 32 ? s_C : 32;
    // exact refine: one wave per contended point; x column read once
    for (int s = wv; s < C; s += 4) {
        int pp = p0 + (int)s_cp[s];
        const float* xc = inp + (size_t)(pp >> 10) * 262144 + (pp & 1023);
        float x0 = xc[(size_t)(lane * 4 + 0) * 1024];
        float x1 = xc[(size_t)(lane * 4 + 1) * 1024];
        float x2 = xc[(size_t)(lane * 4 + 2) * 1024];
        float x3 = xc[(size_t)(lane * 4 + 3) * 1024];
        u64 best = ~0ull;
        int m = (int)s_cm[s];
        for (int c = 0; c < m; ++c) {
            int k = (int)s_ck[s][c];
            float4 wv4 = *(const float4*)(w + (size_t)k * 256 + lane * 4);
            float d0 = x0 - wv4.x, d1 = x1 - wv4.y, d2 = x2 - wv4.z, d3 = x3 - wv4.w;
            float a2 = fmaf(d0, d0, fmaf(d1, d1, fmaf(d2, d2, d3 * d3)));
            #pragma unroll
            for (int m2 = 1; m2 <= 32; m2 <<= 1) a2 += __shfl_xor(a2, m2, 64);
            u64 key = ((u64)sortkey(a2) << 32) | (u32)k;  // tie -> lowest k
            best = key < best ? key : best;
        }
        if (lane == 0) s_res[s] = best;
    }
    __syncthreads();
    if (t < C) {
        u64 r = s_res[t];
        sidx[s_cp[t]] = (int)(r & 1023u);
        sld[s_cp[t]] = inv_sortkey((u32)(r >> 32));  // exact ||x-w||^2
    }
    __syncthreads();
    if (t < 64) atomicAdd(usage + sidx[t], 1.0f);  // integer-valued f32: exact

    // register-transpose gather: thread = (dseg 0..15) x (ptq 0..15)
    {
        int ptq = t & 15, dseg = t >> 4;
        int k0 = sidx[ptq * 4 + 0], k1 = sidx[ptq * 4 + 1];
        int k2 = sidx[ptq * 4 + 2], k3 = sidx[ptq * 4 + 3];
        const float* w0 = w + (size_t)k0 * 256 + dseg * 16;
        const float* w1 = w + (size_t)k1 * 256 + dseg * 16;
        const float* w2 = w + (size_t)k2 * 256 + dseg * 16;
        const float* w3 = w + (size_t)k3 * 256 + dseg * 16;
        float* ob = outq + (size_t)b * 262144 + hw0 + ptq * 4;
        #pragma unroll
        for (int q = 0; q < 4; ++q) {
            float4 a = *(const float4*)(w0 + q * 4);
            float4 bb = *(const float4*)(w1 + q * 4);
            float4 c = *(const float4*)(w2 + q * 4);
            float4 dd = *(const float4*)(w3 + q * 4);
            int d = dseg * 16 + q * 4;
            *(float4*)(ob + (size_t)(d + 0) * 1024) = (float4){a.x, bb.x, c.x, dd.x};
            *(float4*)(ob + (size_t)(d + 1) * 1024) = (float4){a.y, bb.y, c.y, dd.y};
            *(float4*)(ob + (size_t)(d + 2) * 1024) = (float4){a.z, bb.z, c.z, dd.z};
            *(float4*)(ob + (size_t)(d + 3) * 1024) = (float4){a.w, bb.w, c.w, dd.w};
        }
    }

    // block loss partial (fixed-order) + fused final reduce via done counter
    float lsum = (t < 64) ? sld[t] : 0.0f;
    if (wv == 0) {
        #pragma unroll
        for (int off = 32; off >= 1; off >>= 1) lsum += __shfl_xor(lsum, off, 64);
    }
    if (t == 0) {
        partial[blk] = lsum;
        __threadfence();
        amlast = (atomicAdd(done, 1u) == 511u) ? 1u : 0u;
    }
    __syncthreads();
    if (amlast) {
        __threadfence();  // acquire: other blocks' partial writes
        __shared__ float sm[256];
        sm[t] = partial[t] + partial[t + 256];
        __syncthreads();
        #pragma unroll
        for (int off = 128; off >= 1; off >>= 1) {
            if (t < off) sm[t] += sm[t + off];
            __syncthreads();
        }
        if (t == 0) loss[0] = sm[0] * (1.25f / 8388608.0f);
    }
}

extern "C" void kernel_launch(void* const* d_in, const int* in_sizes, int n_in,
                              void* d_out, int out_size, void* d_ws, size_t ws_size,
                              hipStream_t stream) {
    const float* inp = (const float*)d_in[0];
    const float* w = (const float*)d_in[1];
    float* outq = (float*)d_out;
    float* loss = outq + NQ;
    float* usage = outq + NQ + 1;

    char* Aimg = (char*)d_out;  // 16 MiB staging, overwritten by vq_pickgather
    char* ws = (char*)d_ws;
    char* Wimg = ws;                          // 512 KiB
    float* wsq = (float*)(ws + 524288);       // 4 KiB
    u32* best2 = (u32*)(ws + 528384);         // 2 MiB
    float* partial = (float*)(ws + 2625536);  // 2 KiB
    u32* done = (u32*)(ws + 2627584);         // 1 KiB
    float* xsqp = (float*)(ws + 2628608);     // 512 KiB

    vq_conv<<<1152, 256, 0, stream>>>(inp, w, Aimg, Wimg, wsq, usage, done, xsqp);
    vq_coarse<<<2048, 256, 0, stream>>>(Aimg, Wimg, wsq, best2);
    vq_pickgather<<<512, 256, 0, stream>>>(inp, w, best2, xsqp, outq, usage, partial, done,
                                           loss);
}

// Round 12
// 88.125 us; speedup vs baseline: 1.7368x; 1.0613x over previous
//
#include <hip/hip_runtime.h>

// VQ-VAE forward, two-stage argmin, flat single-purpose kernels:
//   1) vq_conv: inputs -> f16 A image + xsq partials; weight -> f16 W image + wsq
//   2) vq_coarse: fp16 MFMA GEMM (K=256) + fused top-2-per-nb candidates
//   3) vq_pick: resolve argmin (exact f32 refine for contended ~8%) -> kidx,
//      loss partials + fused final reduce (done counter)
//   4) vq_gather: flat register-transpose gather, 1KB-contiguous stores, no LDS
//   5) vq_hist: usage via LDS histogram (batched global atomics)
// d_out: [0,8388608) quantized f32 | [8388608] loss | [8388609,+1024) usage
// d_out[0,16MiB) doubles as the f16 A-image (conv -> coarse), overwritten by gather.
// d_ws: Wimg 512K | wsq 4K | best2 2M | partial 2K | done 1K | xsqp 512K | kidx 128K

typedef _Float16 f16;
typedef __attribute__((ext_vector_type(8))) f16 f16x8;
typedef __attribute__((ext_vector_type(4))) float f32x4;
typedef unsigned int u32;
typedef unsigned long long u64;

#define NQ 8388608

__device__ __forceinline__ u32 sortkey(float f) {
    u32 u = __float_as_uint(f);
    return (u & 0x80000000u) ? ~u : (u | 0x80000000u);
}
__device__ __forceinline__ float inv_sortkey(u32 u) {
    return (u & 0x80000000u) ? __uint_as_float(u & 0x7FFFFFFFu) : __uint_as_float(~u);
}

// ---- merged conversion kernel ----
extern "C" __global__ __launch_bounds__(256) void vq_conv(const float* __restrict__ inp,
                                                          const float* __restrict__ w,
                                                          char* __restrict__ Aimg,
                                                          char* __restrict__ Wimg,
                                                          float* __restrict__ wsq,
                                                          float* __restrict__ usage,
                                                          u32* __restrict__ done,
                                                          float* __restrict__ xsqp) {
    int blk = blockIdx.x, tid = threadIdx.x;
    if (blk < 1024) {
        __shared__ float xt[64 * 128];
        int mb = blk >> 2, dcb = blk & 3;
        int b = mb >> 3, hw0 = (mb & 7) * 128;
        const float* base = inp + (size_t)b * 262144 + hw0;
        char* Ab = Aimg + (size_t)mb * 65536;
        #pragma unroll
        for (int it = 0; it < 8; ++it) {
            int e = it * 256 + tid;
            int dd = e >> 5, h4 = e & 31;
            float4 v = *(const float4*)(base + (size_t)(dcb * 64 + dd) * 1024 + h4 * 4);
            *(float4*)(xt + dd * 128 + h4 * 4) = v;
        }
        __syncthreads();
        #pragma unroll
        for (int it2 = 0; it2 < 4; ++it2) {
            int task = it2 * 256 + tid;
            int g = task >> 7, row = task & 127;
            union { f16 h[8]; uint4 v; } pk;
            #pragma unroll
            for (int j = 0; j < 8; ++j) pk.h[j] = (f16)xt[(g * 8 + j) * 128 + row];
            int t_img = dcb * 2 + (g >> 2), cg = g & 3;
            *(uint4*)(Ab + (size_t)t_img * 8192 + cg * 2048 + row * 16) = pk.v;
        }
        if (tid < 128) {
            float s = 0.0f;
            #pragma unroll 8
            for (int dd = 0; dd < 64; ++dd) {
                float x = xt[dd * 128 + tid];
                s = fmaf(x, x, s);
            }
            xsqp[dcb * 32768 + mb * 128 + tid] = s;
        }
    } else {
        if (blk == 1024 && tid == 0) done[0] = 0;
        int gid = (blk - 1024) * 256 + tid;  // 32768 = 1024 n x 32 dc
        int n = gid >> 5, dc = gid & 31;
        const float* src = w + n * 256 + dc * 8;
        float4 v0 = *(const float4*)src;
        float4 v1 = *(const float4*)(src + 4);
        float xs[8] = {v0.x, v0.y, v0.z, v0.w, v1.x, v1.y, v1.z, v1.w};
        union { f16 h[8]; uint4 v; } pk;
        float sq = 0.0f;
        #pragma unroll
        for (int j = 0; j < 8; ++j) {
            pk.h[j] = (f16)xs[j];
            sq += xs[j] * xs[j];
        }
        int nb = n >> 7, col = n & 127;
        *(uint4*)(Wimg + (size_t)nb * 65536 + (dc >> 2) * 8192 + (dc & 3) * 2048 + col * 16) = pk.v;
        #pragma unroll
        for (int m = 1; m <= 16; m <<= 1) sq += __shfl_xor(sq, m, 64);
        if ((tid & 31) == 0) { wsq[n] = sq; usage[n] = 0.0f; }
    }
}

// ---- coarse fp16 GEMM 128x128xK256 + fused top-2-per-nb argmin ----
extern "C" __global__ __launch_bounds__(256) void vq_coarse(const char* __restrict__ Aimg,
                                                            const char* __restrict__ Wimg,
                                                            const float* __restrict__ wsq,
                                                            u32* __restrict__ best2) {
    __shared__ __align__(16) char smem[32768];  // 2 bufs x (A 8K + B 8K)
    __shared__ u32 red2[128][2][2];
    const int tid = threadIdx.x, lane = tid & 63, wv = tid >> 6;
    const int wm = wv >> 1, wn = wv & 1;
    const int rm = wm * 64, cn = wn * 64;
    const int cg = lane >> 4, rl = lane & 15;
    int bid = blockIdx.x;
    int lb = (bid & 7) * 256 + (bid >> 3);  // XCD-chunked swizzle (2048 % 8 == 0)
    const int mb = lb >> 3, nb = lb & 7;

    const char* Ag = Aimg + (size_t)mb * 65536;
    const char* Bg = Wimg + (size_t)nb * 65536;

    f32x4 acc[4][4];
    #pragma unroll
    for (int i = 0; i < 4; ++i)
        #pragma unroll
        for (int j = 0; j < 4; ++j) acc[i][j] = (f32x4){0.f, 0.f, 0.f, 0.f};

    auto stage = [&](int T) {
        const char* ga = Ag + (size_t)T * 8192;
        const char* gb = Bg + (size_t)T * 8192;
        char* la = smem + (T & 1) * 16384;
        char* lb2 = la + 8192;
        __builtin_amdgcn_global_load_lds(
            (const __attribute__((address_space(1))) u32*)(ga + tid * 16),
            (__attribute__((address_space(3))) u32*)(la + tid * 16), 16, 0, 0);
        __builtin_amdgcn_global_load_lds(
            (const __attribute__((address_space(1))) u32*)(ga + tid * 16 + 4096),
            (__attribute__((address_space(3))) u32*)(la + tid * 16 + 4096), 16, 0, 0);
        __builtin_amdgcn_global_load_lds(
            (const __attribute__((address_space(1))) u32*)(gb + tid * 16),
            (__attribute__((address_space(3))) u32*)(lb2 + tid * 16), 16, 0, 0);
        __builtin_amdgcn_global_load_lds(
            (const __attribute__((address_space(1))) u32*)(gb + tid * 16 + 4096),
            (__attribute__((address_space(3))) u32*)(lb2 + tid * 16 + 4096), 16, 0, 0);
    };

    stage(0);
    asm volatile("s_waitcnt vmcnt(0)" ::: "memory");
    __builtin_amdgcn_s_barrier();

    for (int T = 0; T < 8; ++T) {
        if (T < 7) stage(T + 1);
        const char* Ab = smem + (T & 1) * 16384 + cg * 2048;
        const char* Bb = Ab + 8192;
        f16x8 af[4], bf[4];
        #pragma unroll
        for (int f = 0; f < 4; ++f) {
            af[f] = *(const f16x8*)(Ab + (rm + f * 16 + rl) * 16);
            bf[f] = *(const f16x8*)(Bb + (cn + f * 16 + rl) * 16);
        }
        __builtin_amdgcn_sched_barrier(0);
        asm volatile("s_waitcnt lgkmcnt(0)" ::: "memory");
        __builtin_amdgcn_sched_barrier(0);
        __builtin_amdgcn_s_setprio(1);
        #pragma unroll
        for (int fi = 0; fi < 4; ++fi)
            #pragma unroll
            for (int fj = 0; fj < 4; ++fj)
                acc[fi][fj] = __builtin_amdgcn_mfma_f32_16x16x32_f16(af[fi], bf[fj],
                                                                    acc[fi][fj], 0, 0, 0);
        __builtin_amdgcn_s_setprio(0);
        __builtin_amdgcn_sched_barrier(0);
        asm volatile("s_waitcnt vmcnt(0)" ::: "memory");
        __builtin_amdgcn_s_barrier();
    }

    // top-2 per point within this nb: key = (sortkey(dist) & ~1023) | n
    float wq[4];
    #pragma unroll
    for (int fj = 0; fj < 4; ++fj) wq[fj] = wsq[nb * 128 + cn + fj * 16 + rl];

    #pragma unroll
    for (int fi = 0; fi < 4; ++fi) {
        #pragma unroll
        for (int r = 0; r < 4; ++r) {
            u32 b = 0xFFFFFFFFu, s = 0xFFFFFFFFu;
            #pragma unroll
            for (int fj = 0; fj < 4; ++fj) {
                float dist = wq[fj] - 2.0f * acc[fi][fj][r];
                u32 n = (u32)(nb * 128 + cn + fj * 16 + rl);
                u32 cand = (sortkey(dist) & 0xFFFFFC00u) | n;
                if (cand < b) { s = b; b = cand; }
                else if (cand < s) { s = cand; }
            }
            #pragma unroll
            for (int m2 = 1; m2 <= 8; m2 <<= 1) {
                u32 qb = (u32)__shfl_xor((int)b, m2, 64);
                u32 qs = (u32)__shfl_xor((int)s, m2, 64);
                u32 hi = b > qb ? b : qb;
                b = b < qb ? b : qb;
                s = s < qs ? s : qs;
                s = s < hi ? s : hi;
            }
            if (rl == 0) {
                int mloc = rm + fi * 16 + cg * 4 + r;
                red2[mloc][wn][0] = b;
                red2[mloc][wn][1] = s;
            }
        }
    }
    __syncthreads();
    if (tid < 128) {
        u32 b0 = red2[tid][0][0], s0 = red2[tid][0][1];
        u32 b1 = red2[tid][1][0], s1 = red2[tid][1][1];
        u32 B = b0 < b1 ? b0 : b1;
        u32 hi = b0 > b1 ? b0 : b1;
        u32 S = s0 < s1 ? s0 : s1;
        S = S < hi ? S : hi;
        u32* dst = best2 + ((size_t)mb * 128 + tid) * 16 + nb * 2;
        dst[0] = B;
        dst[1] = S;
    }
}

// ---- pick: resolve argmin -> kidx; loss partial + fused final (done counter) ----
extern "C" __global__ __launch_bounds__(256) void vq_pick(const float* __restrict__ inp,
                                                          const float* __restrict__ w,
                                                          const u32* __restrict__ best2,
                                                          const float* __restrict__ xsqp,
                                                          int* __restrict__ kidx,
                                                          float* __restrict__ partial,
                                                          u32* __restrict__ done,
                                                          float* __restrict__ loss) {
    __shared__ int sidx[64];
    __shared__ float sld[64];
    __shared__ u32 s_cp[32];
    __shared__ u32 s_cm[32];
    __shared__ u32 s_ck[32][8];
    __shared__ u64 s_res[32];
    __shared__ int s_C;
    __shared__ u32 amlast;

    int blk = blockIdx.x, t = threadIdx.x;
    int lane = t & 63, wv = t >> 6;
    int p0 = blk * 64;
    if (t == 0) s_C = 0;
    __syncthreads();

    if (t < 64) {
        int p = p0 + t;
        const uint4* cp = (const uint4*)(best2 + (size_t)p * 16);
        uint4 q0 = cp[0], q1 = cp[1], q2 = cp[2], q3 = cp[3];
        u32 ca[16] = {q0.x, q0.y, q0.z, q0.w, q1.x, q1.y, q1.z, q1.w,
                      q2.x, q2.y, q2.z, q2.w, q3.x, q3.y, q3.z, q3.w};
        u32 minc = ca[0];
        #pragma unroll
        for (int c = 1; c < 16; ++c) minc = ca[c] < minc ? ca[c] : minc;
        float dmin = inv_sortkey(minc & 0xFFFFFC00u);
        float thr = dmin + 1.0f;  // coarse err (~0.05) << 1.0 << typical gap (~13)
        u32 ks[8];
        int m = 0;
        #pragma unroll
        for (int c = 0; c < 16; ++c) {
            if (inv_sortkey(ca[c] & 0xFFFFFC00u) <= thr) {
                if (m < 8) ks[m] = ca[c] & 1023u;
                ++m;
            }
        }
        if (m > 8) m = 8;
        float xs = (xsqp[p] + xsqp[32768 + p]) + (xsqp[65536 + p] + xsqp[98304 + p]);
        if (m <= 1) {  // uncontended: coarse key IS the argmin; loss via identity
            sidx[t] = (int)(minc & 1023u);
            sld[t] = xs + dmin;
        } else {
            int slot = atomicAdd(&s_C, 1);
            if (slot < 32) {
                s_cp[slot] = (u32)t;
                s_cm[slot] = (u32)m;
                for (int i = 0; i < m; ++i) s_ck[slot][i] = ks[i];
            } else {  // statistically impossible overflow: graceful fallback
                sidx[t] = (int)(minc & 1023u);
                sld[t] = xs + dmin;
            }
        }
    }
    __syncthreads();
    int C = s_C < 32 ? s_C : 32;
    // exact refine: one wave per contended point; x column read once
    for (int s = wv; s < C; s += 4) {
        int pp = p0 + (int)s_cp[s];
        const float* xc = inp + (size_t)(pp >> 10) * 262144 + (pp & 1023);
        float x0 = xc[(size_t)(lane * 4 + 0) * 1024];
        float x1 = xc[(size_t)(lane * 4 + 1) * 1024];
        float x2 = xc[(size_t)(lane * 4 + 2) * 1024];
        float x3 = xc[(size_t)(lane * 4 + 3) * 1024];
        u64 best = ~0ull;
        int m = (int)s_cm[s];
        for (int c = 0; c < m; ++c) {
            int k = (int)s_ck[s][c];
            float4 wv4 = *(const float4*)(w + (size_t)k * 256 + lane * 4);
            float d0 = x0 - wv4.x, d1 = x1 - wv4.y, d2 = x2 - wv4.z, d3 = x3 - wv4.w;
            float a2 = fmaf(d0, d0, fmaf(d1, d1, fmaf(d2, d2, d3 * d3)));
            #pragma unroll
            for (int m2 = 1; m2 <= 32; m2 <<= 1) a2 += __shfl_xor(a2, m2, 64);
            u64 key = ((u64)sortkey(a2) << 32) | (u32)k;  // tie -> lowest k
            best = key < best ? key : best;
        }
        if (lane == 0) s_res[s] = best;
    }
    __syncthreads();
    if (t < C) {
        u64 r = s_res[t];
        sidx[s_cp[t]] = (int)(r & 1023u);
        sld[s_cp[t]] = inv_sortkey((u32)(r >> 32));  // exact ||x-w||^2
    }
    __syncthreads();
    if (t < 64) kidx[p0 + t] = sidx[t];

    // block loss partial (fixed-order) + fused final reduce via done counter
    float lsum = (t < 64) ? sld[t] : 0.0f;
    if (wv == 0) {
        #pragma unroll
        for (int off = 32; off >= 1; off >>= 1) lsum += __shfl_xor(lsum, off, 64);
    }
    if (t == 0) {
        partial[blk] = lsum;
        __threadfence();
        amlast = (atomicAdd(done, 1u) == 511u) ? 1u : 0u;
    }
    __syncthreads();
    if (amlast) {
        __threadfence();  // acquire: other blocks' partial writes
        __shared__ float sm[256];
        sm[t] = partial[t] + partial[t + 256];
        __syncthreads();
        #pragma unroll
        for (int off = 128; off >= 1; off >>= 1) {
            if (t < off) sm[t] += sm[t + off];
            __syncthreads();
        }
        if (t == 0) loss[0] = sm[0] * (1.25f / 8388608.0f);
    }
}

// ---- gather: flat register transpose, 1KB-contiguous stores, no LDS/barriers ----
extern "C" __global__ __launch_bounds__(256) void vq_gather(const float* __restrict__ w,
                                                            const int* __restrict__ kidx,
                                                            float* __restrict__ outq) {
    int blk = blockIdx.x;  // 2048 = tile(128) x dseg(16)
    int tile = blk >> 4, dseg = blk & 15;
    int lane = threadIdx.x & 63, wv = threadIdx.x >> 6;
    int p0 = tile * 256;   // 256-point tile (never crosses batch row group)
    int b = p0 >> 10, hw0 = p0 & 1023;

    int4 kv = *(const int4*)(kidx + p0 + lane * 4);
    int d0 = dseg * 16 + wv * 4;
    const float* w0 = w + (size_t)kv.x * 256 + d0;
    const float* w1 = w + (size_t)kv.y * 256 + d0;
    const float* w2 = w + (size_t)kv.z * 256 + d0;
    const float* w3 = w + (size_t)kv.w * 256 + d0;
    float* ob = outq + (size_t)b * 262144 + hw0 + lane * 4;

    float4 a = *(const float4*)w0;
    float4 bb = *(const float4*)w1;
    float4 c = *(const float4*)w2;
    float4 dd = *(const float4*)w3;
    *(float4*)(ob + (size_t)(d0 + 0) * 1024) = (float4){a.x, bb.x, c.x, dd.x};
    *(float4*)(ob + (size_t)(d0 + 1) * 1024) = (float4){a.y, bb.y, c.y, dd.y};
    *(float4*)(ob + (size_t)(d0 + 2) * 1024) = (float4){a.z, bb.z, c.z, dd.z};
    *(float4*)(ob + (size_t)(d0 + 3) * 1024) = (float4){a.w, bb.w, c.w, dd.w};
}

// ---- usage histogram: LDS hist per 1024-pt block, batched global atomics ----
extern "C" __global__ __launch_bounds__(256) void vq_hist(const int* __restrict__ kidx,
                                                          float* __restrict__ usage) {
    __shared__ u32 h[1024];
    int blk = blockIdx.x, t = threadIdx.x;
    #pragma unroll
    for (int i = 0; i < 4; ++i) h[i * 256 + t] = 0;
    __syncthreads();
    int4 kv = *(const int4*)(kidx + blk * 1024 + t * 4);
    atomicAdd(&h[kv.x], 1u);
    atomicAdd(&h[kv.y], 1u);
    atomicAdd(&h[kv.z], 1u);
    atomicAdd(&h[kv.w], 1u);
    __syncthreads();
    #pragma unroll
    for (int i = 0; i < 4; ++i) {
        u32 cnt = h[i * 256 + t];
        if (cnt) atomicAdd(usage + i * 256 + t, (float)cnt);  // integer-exact
    }
}

extern "C" void kernel_launch(void* const* d_in, const int* in_sizes, int n_in,
                              void* d_out, int out_size, void* d_ws, size_t ws_size,
                              hipStream_t stream) {
    const float* inp = (const float*)d_in[0];
    const float* w = (const float*)d_in[1];
    float* outq = (float*)d_out;
    float* loss = outq + NQ;
    float* usage = outq + NQ + 1;

    char* Aimg = (char*)d_out;  // 16 MiB staging, overwritten by vq_gather
    char* ws = (char*)d_ws;
    char* Wimg = ws;                          // 512 KiB
    float* wsq = (float*)(ws + 524288);       // 4 KiB
    u32* best2 = (u32*)(ws + 528384);         // 2 MiB
    float* partial = (float*)(ws + 2625536);  // 2 KiB
    u32* done = (u32*)(ws + 2627584);         // 1 KiB
    float* xsqp = (float*)(ws + 2628608);     // 512 KiB
    int* kidx = (int*)(ws + 3152896);         // 128 KiB

    vq_conv<<<1152, 256, 0, stream>>>(inp, w, Aimg, Wimg, wsq, usage, done, xsqp);
    vq_coarse<<<2048, 256, 0, stream>>>(Aimg, Wimg, wsq, best2);
    vq_pick<<<512, 256, 0, stream>>>(inp, w, best2, xsqp, kidx, partial, done, loss);
    vq_gather<<<2048, 256, 0, stream>>>(w, kidx, outq);
    vq_hist<<<32, 256, 0, stream>>>(kidx, usage);
}